// Round 1
// baseline (2751.152 us; speedup 1.0000x reference)
//
#include <hip/hip_runtime.h>
#include <hip/hip_bf16.h>

typedef __attribute__((ext_vector_type(4))) float f32x4;
typedef __attribute__((ext_vector_type(4))) int   i32x4;
typedef __attribute__((ext_vector_type(8))) short s16x8;

#define MDIM 8192
#define KDIM 4096
#define NDIM 16384
#define BK   32
#define NKT  (KDIM / BK)   // 128 K-tiles

static __device__ __forceinline__ short f2bf(float f) {
    __bf16 h = (__bf16)f;               // RNE fp32->bf16, native on gfx950
    return __builtin_bit_cast(short, h);
}

__global__ __launch_bounds__(256, 2)
void sl_gemm(const float* __restrict__ X, const int* __restrict__ Wq,
             const float* __restrict__ scale_p, const float* __restrict__ bias,
             float* __restrict__ Out)
{
    // 128x32 bf16 tiles, stored as 16B slots with XOR swizzle (conflict-free ds_read_b128)
    __shared__ s16x8 As[128 * 4];
    __shared__ s16x8 Bs[128 * 4];

    const int t    = threadIdx.x;
    const int lane = t & 63;
    const int wave = t >> 6;
    const int wr   = wave >> 1;          // 2x2 wave grid, each wave 64x64 out
    const int wc   = wave & 1;

    // ---- tile mapping: XCD swizzle (8192 blocks, %8==0 -> bijective) then
    //      16-wide tn panels, tm-fastest within a panel (B-panel L2/L3 reuse)
    int bid = blockIdx.x;
    int swz = (bid & 7) * 1024 + (bid >> 3);
    int panel   = swz >> 10;             // 8 panels of 64tm x 16tn
    int inpanel = swz & 1023;
    int tn = (panel << 4) + (inpanel >> 6);
    int tm = inpanel & 63;
    const int m0 = tm << 7;
    const int n0 = tn << 7;

    // ---- staging: thread t owns (row = t>>1, 16 consecutive k at (t&1)*16)
    const int srow  = t >> 1;
    const int shalf = t & 1;
    const float* Xp = X  + (size_t)(m0 + srow) * KDIM + shalf * 16;
    const int*   Wp = Wq + (size_t)(n0 + srow) * KDIM + shalf * 16;

    f32x4 acc[4][4];
    #pragma unroll
    for (int i = 0; i < 4; ++i)
        #pragma unroll
        for (int j = 0; j < 4; ++j)
            acc[i][j] = (f32x4){0.f, 0.f, 0.f, 0.f};

    const int fr = lane & 15;            // fragment row/col within 16
    const int fs = lane >> 4;            // k-slot (8 bf16 each)

    // register prefetch buffers (raw dtypes; convert at store time so the
    // prefetch loads overlap with MFMA, not with the conversion)
    f32x4 ar[4];
    i32x4 br[4];
    #pragma unroll
    for (int p = 0; p < 4; ++p) {
        ar[p] = *(const f32x4*)(Xp + p * 4);
        br[p] = *(const i32x4*)(Wp + p * 4);
    }

    const int wbase = srow * 4;
    const int wswz  = (srow >> 1) & 3;
    const int ws0   = (shalf * 2)     ^ wswz;
    const int ws1   = (shalf * 2 + 1) ^ wswz;

    for (int kt = 0; kt < NKT; ++kt) {
        __syncthreads();                 // previous tile's LDS reads done
        // ---- convert + LDS store (slots of 8 bf16, swizzled)
        {
            s16x8 v0, v1;
            #pragma unroll
            for (int q = 0; q < 8; ++q) v0[q] = f2bf(ar[q >> 2][q & 3]);
            #pragma unroll
            for (int q = 0; q < 8; ++q) v1[q] = f2bf(ar[2 + (q >> 2)][q & 3]);
            As[wbase + ws0] = v0;
            As[wbase + ws1] = v1;
            s16x8 u0, u1;
            #pragma unroll
            for (int q = 0; q < 8; ++q) u0[q] = f2bf((float)br[q >> 2][q & 3]);
            #pragma unroll
            for (int q = 0; q < 8; ++q) u1[q] = f2bf((float)br[2 + (q >> 2)][q & 3]);
            Bs[wbase + ws0] = u0;
            Bs[wbase + ws1] = u1;
        }
        __syncthreads();

        // ---- issue next tile's global loads (overlap with MFMA below)
        if (kt + 1 < NKT) {
            const float* Xn = Xp + (size_t)(kt + 1) * BK;
            const int*   Wn = Wp + (size_t)(kt + 1) * BK;
            #pragma unroll
            for (int p = 0; p < 4; ++p) {
                ar[p] = *(const f32x4*)(Xn + p * 4);
                br[p] = *(const i32x4*)(Wn + p * 4);
            }
        }

        // ---- fragments + 16 MFMA
        s16x8 af[4], bq[4];
        #pragma unroll
        for (int i = 0; i < 4; ++i) {
            int row = wr * 64 + i * 16 + fr;
            af[i] = As[row * 4 + (fs ^ ((row >> 1) & 3))];
        }
        #pragma unroll
        for (int j = 0; j < 4; ++j) {
            int col = wc * 64 + j * 16 + fr;
            bq[j] = Bs[col * 4 + (fs ^ ((col >> 1) & 3))];
        }
        #pragma unroll
        for (int i = 0; i < 4; ++i)
            #pragma unroll
            for (int j = 0; j < 4; ++j)
                acc[i][j] = __builtin_amdgcn_mfma_f32_16x16x32_bf16(
                    af[i], bq[j], acc[i][j], 0, 0, 0);
    }

    // ---- epilogue: D col = lane&15, row = (lane>>4)*4 + q; apply scale+bias
    const float scale = scale_p[0];
    #pragma unroll
    for (int j = 0; j < 4; ++j) {
        const int c  = n0 + wc * 64 + j * 16 + fr;
        const float bj = bias[c];
        #pragma unroll
        for (int i = 0; i < 4; ++i) {
            const int r0 = m0 + wr * 64 + i * 16 + fs * 4;
            float* op = Out + (size_t)r0 * NDIM + c;
            #pragma unroll
            for (int q = 0; q < 4; ++q)
                op[(size_t)q * NDIM] = acc[i][j][q] * scale + bj;
        }
    }
}

extern "C" void kernel_launch(void* const* d_in, const int* in_sizes, int n_in,
                              void* d_out, int out_size, void* d_ws, size_t ws_size,
                              hipStream_t stream) {
    const float* X     = (const float*)d_in[0];
    const int*   Wq    = (const int*)d_in[1];   // int8 widened to int32 by harness
    const float* scale = (const float*)d_in[2];
    const float* bias  = (const float*)d_in[3];
    float*       Out   = (float*)d_out;

    dim3 grid(8192), block(256);
    hipLaunchKernelGGL(sl_gemm, grid, block, 0, stream, X, Wq, scale, bias, Out);
}

// Round 2
// 1438.938 us; speedup vs baseline: 1.9119x; 1.9119x over previous
//
#include <hip/hip_runtime.h>
#include <hip/hip_bf16.h>

typedef __attribute__((ext_vector_type(4))) float f32x4;
typedef __attribute__((ext_vector_type(4))) int   i32x4;
typedef __attribute__((ext_vector_type(8))) short s16x8;
typedef unsigned short ushort_t;

#define MDIM 8192
#define KDIM 4096
#define NDIM 16384

static __device__ __forceinline__ short f2bf(float f) {
    __bf16 h = (__bf16)f;               // RNE fp32->bf16, native on gfx950
    return __builtin_bit_cast(short, h);
}

static __device__ __forceinline__ void gload_lds16(const void* g, void* l) {
    __builtin_amdgcn_global_load_lds(
        (const __attribute__((address_space(1))) unsigned int*)g,
        (__attribute__((address_space(3))) unsigned int*)l,
        16, 0, 0);
}

// ---------------- convert kernels (memory-bound, vectorized) ----------------

__global__ __launch_bounds__(256)
void cvt_f32_bf16(const float* __restrict__ in, ushort_t* __restrict__ out, int n8) {
    for (int i = blockIdx.x * blockDim.x + threadIdx.x; i < n8;
         i += gridDim.x * blockDim.x) {
        f32x4 a = ((const f32x4*)in)[i * 2];
        f32x4 b = ((const f32x4*)in)[i * 2 + 1];
        s16x8 o;
        #pragma unroll
        for (int q = 0; q < 4; ++q) o[q] = f2bf(a[q]);
        #pragma unroll
        for (int q = 0; q < 4; ++q) o[4 + q] = f2bf(b[q]);
        ((s16x8*)out)[i] = o;
    }
}

__global__ __launch_bounds__(256)
void cvt_i32_bf16(const int* __restrict__ in, ushort_t* __restrict__ out, int n8) {
    for (int i = blockIdx.x * blockDim.x + threadIdx.x; i < n8;
         i += gridDim.x * blockDim.x) {
        i32x4 a = ((const i32x4*)in)[i * 2];
        i32x4 b = ((const i32x4*)in)[i * 2 + 1];
        s16x8 o;
        #pragma unroll
        for (int q = 0; q < 4; ++q) o[q] = f2bf((float)a[q]);   // |v|<=127: exact
        #pragma unroll
        for (int q = 0; q < 4; ++q) o[4 + q] = f2bf((float)b[q]);
        ((s16x8*)out)[i] = o;
    }
}

// ---------------- bf16 GEMM, m97 structure ----------------
// C[m][n] = sum_k A[m][k]*B[n][k]  (both operands K-major, 128x128 tile, BK=64)
// LDS tiles: [128 rows][8 slots of 16B], physical slot = logical ^ (row&7)
// (swizzle applied on the GLOBAL source address; LDS dest stays linear)

__global__ __launch_bounds__(256, 2)
void sl_gemm_bf16(const ushort_t* __restrict__ A, const ushort_t* __restrict__ Bw,
                  const float* __restrict__ scale_p, const float* __restrict__ bias,
                  float* __restrict__ Out)
{
    __shared__ s16x8 As[1024];   // 16 KB
    __shared__ s16x8 Bs[1024];   // 16 KB

    const int t    = threadIdx.x;
    const int lane = t & 63;
    const int wave = t >> 6;
    const int wr   = wave >> 1;          // 2x2 wave grid, 64x64 out each
    const int wc   = wave & 1;

    // XCD-bijective swizzle (8192 % 8 == 0), then 16-tn panels, tm fastest
    int bid = blockIdx.x;
    int swz = (bid & 7) * 1024 + (bid >> 3);
    int panel   = swz >> 10;
    int inpanel = swz & 1023;
    int tn = (panel << 4) + (inpanel >> 6);
    int tm = inpanel & 63;
    const int m0 = tm << 7;
    const int n0 = tn << 7;

    // ---- staging geometry: chunk c = wave*4+i covers rows c*8..c*8+7
    const int lrow = lane >> 3;               // row within chunk (== row&7)
    const int lcs  = (lane & 7) ^ lrow;       // swizzled logical col-slot
    const ushort_t* baseA = A  + (size_t)(m0 + wave * 32 + lrow) * KDIM + lcs * 8;
    const ushort_t* baseB = Bw + (size_t)(n0 + wave * 32 + lrow) * KDIM + lcs * 8;

    // ---- ds_read fragment byte offsets (constant across K loop)
    const int fr = lane & 15;
    const int fs = lane >> 4;                 // 0..3
    int aOff[4][2], bOff[4][2];
    #pragma unroll
    for (int i = 0; i < 4; ++i) {
        int ra = wr * 64 + i * 16 + fr;
        int rb = wc * 64 + i * 16 + fr;
        #pragma unroll
        for (int kk = 0; kk < 2; ++kk) {
            aOff[i][kk] = ra * 128 + (((kk * 4 + fs) ^ (ra & 7)) * 16);
            bOff[i][kk] = rb * 128 + (((kk * 4 + fs) ^ (rb & 7)) * 16);
        }
    }
    const char* AsB = (const char*)As;
    const char* BsB = (const char*)Bs;

    f32x4 acc[4][4];
    #pragma unroll
    for (int i = 0; i < 4; ++i)
        #pragma unroll
        for (int j = 0; j < 4; ++j)
            acc[i][j] = (f32x4){0.f, 0.f, 0.f, 0.f};

    // prologue: stage tile 0
    #pragma unroll
    for (int i = 0; i < 4; ++i) {
        gload_lds16(baseA + (size_t)i * (8 * KDIM), (char*)As + (wave * 4 + i) * 1024);
        gload_lds16(baseB + (size_t)i * (8 * KDIM), (char*)Bs + (wave * 4 + i) * 1024);
    }

    const int NKT = KDIM / 64;   // 64 K-steps
    for (int kt = 0; kt < NKT; ++kt) {
        __syncthreads();   // staging complete (compiler drains vmcnt before barrier)

        s16x8 af[4][2], bq[4][2];
        #pragma unroll
        for (int i = 0; i < 4; ++i)
            #pragma unroll
            for (int kk = 0; kk < 2; ++kk) {
                af[i][kk] = *(const s16x8*)(AsB + aOff[i][kk]);
                bq[i][kk] = *(const s16x8*)(BsB + bOff[i][kk]);
            }

        #pragma unroll
        for (int kk = 0; kk < 2; ++kk)
            #pragma unroll
            for (int i = 0; i < 4; ++i)
                #pragma unroll
                for (int j = 0; j < 4; ++j)
                    acc[i][j] = __builtin_amdgcn_mfma_f32_16x16x32_bf16(
                        af[i][kk], bq[j][kk], acc[i][j], 0, 0, 0);

        __syncthreads();   // all lanes done reading LDS before overwrite
        if (kt + 1 < NKT) {
            const size_t ko = (size_t)(kt + 1) * 64;
            #pragma unroll
            for (int i = 0; i < 4; ++i) {
                gload_lds16(baseA + (size_t)i * (8 * KDIM) + ko,
                            (char*)As + (wave * 4 + i) * 1024);
                gload_lds16(baseB + (size_t)i * (8 * KDIM) + ko,
                            (char*)Bs + (wave * 4 + i) * 1024);
            }
        }
    }

    // ---- epilogue: D col = lane&15, row = (lane>>4)*4 + q
    const float scale = scale_p[0];
    #pragma unroll
    for (int j = 0; j < 4; ++j) {
        const int c   = n0 + wc * 64 + j * 16 + fr;
        const float bj = bias[c];
        #pragma unroll
        for (int i = 0; i < 4; ++i) {
            const int r0 = m0 + wr * 64 + i * 16 + fs * 4;
            float* op = Out + (size_t)r0 * NDIM + c;
            #pragma unroll
            for (int q = 0; q < 4; ++q)
                op[(size_t)q * NDIM] = acc[i][j][q] * scale + bj;
        }
    }
}

// ---------------- fallback (round-1 kernel, fp32 direct) ----------------

__global__ __launch_bounds__(256, 2)
void sl_gemm_fb(const float* __restrict__ X, const int* __restrict__ Wq,
                const float* __restrict__ scale_p, const float* __restrict__ bias,
                float* __restrict__ Out)
{
    __shared__ s16x8 As[128 * 4];
    __shared__ s16x8 Bs[128 * 4];

    const int t    = threadIdx.x;
    const int lane = t & 63;
    const int wave = t >> 6;
    const int wr   = wave >> 1;
    const int wc   = wave & 1;

    int bid = blockIdx.x;
    int swz = (bid & 7) * 1024 + (bid >> 3);
    int panel   = swz >> 10;
    int inpanel = swz & 1023;
    int tn = (panel << 4) + (inpanel >> 6);
    int tm = inpanel & 63;
    const int m0 = tm << 7;
    const int n0 = tn << 7;

    const int srow  = t >> 1;
    const int shalf = t & 1;
    const float* Xp = X  + (size_t)(m0 + srow) * KDIM + shalf * 16;
    const int*   Wp = Wq + (size_t)(n0 + srow) * KDIM + shalf * 16;

    f32x4 acc[4][4];
    #pragma unroll
    for (int i = 0; i < 4; ++i)
        #pragma unroll
        for (int j = 0; j < 4; ++j)
            acc[i][j] = (f32x4){0.f, 0.f, 0.f, 0.f};

    const int fr = lane & 15;
    const int fs = lane >> 4;

    f32x4 ar[4];
    i32x4 br[4];
    #pragma unroll
    for (int p = 0; p < 4; ++p) {
        ar[p] = *(const f32x4*)(Xp + p * 4);
        br[p] = *(const i32x4*)(Wp + p * 4);
    }

    const int wbase = srow * 4;
    const int wswz  = (srow >> 1) & 3;
    const int ws0   = (shalf * 2)     ^ wswz;
    const int ws1   = (shalf * 2 + 1) ^ wswz;

    for (int kt = 0; kt < KDIM / 32; ++kt) {
        __syncthreads();
        {
            s16x8 v0, v1;
            #pragma unroll
            for (int q = 0; q < 8; ++q) v0[q] = f2bf(ar[q >> 2][q & 3]);
            #pragma unroll
            for (int q = 0; q < 8; ++q) v1[q] = f2bf(ar[2 + (q >> 2)][q & 3]);
            As[wbase + ws0] = v0;
            As[wbase + ws1] = v1;
            s16x8 u0, u1;
            #pragma unroll
            for (int q = 0; q < 8; ++q) u0[q] = f2bf((float)br[q >> 2][q & 3]);
            #pragma unroll
            for (int q = 0; q < 8; ++q) u1[q] = f2bf((float)br[2 + (q >> 2)][q & 3]);
            Bs[wbase + ws0] = u0;
            Bs[wbase + ws1] = u1;
        }
        __syncthreads();

        if (kt + 1 < KDIM / 32) {
            const float* Xn = Xp + (size_t)(kt + 1) * 32;
            const int*   Wn = Wp + (size_t)(kt + 1) * 32;
            #pragma unroll
            for (int p = 0; p < 4; ++p) {
                ar[p] = *(const f32x4*)(Xn + p * 4);
                br[p] = *(const i32x4*)(Wn + p * 4);
            }
        }

        s16x8 af[4], bq[4];
        #pragma unroll
        for (int i = 0; i < 4; ++i) {
            int row = wr * 64 + i * 16 + fr;
            af[i] = As[row * 4 + (fs ^ ((row >> 1) & 3))];
        }
        #pragma unroll
        for (int j = 0; j < 4; ++j) {
            int col = wc * 64 + j * 16 + fr;
            bq[j] = Bs[col * 4 + (fs ^ ((col >> 1) & 3))];
        }
        #pragma unroll
        for (int i = 0; i < 4; ++i)
            #pragma unroll
            for (int j = 0; j < 4; ++j)
                acc[i][j] = __builtin_amdgcn_mfma_f32_16x16x32_bf16(
                    af[i], bq[j], acc[i][j], 0, 0, 0);
    }

    const float scale = scale_p[0];
    #pragma unroll
    for (int j = 0; j < 4; ++j) {
        const int c  = n0 + wc * 64 + j * 16 + fr;
        const float bj = bias[c];
        #pragma unroll
        for (int i = 0; i < 4; ++i) {
            const int r0 = m0 + wr * 64 + i * 16 + fs * 4;
            float* op = Out + (size_t)r0 * NDIM + c;
            #pragma unroll
            for (int q = 0; q < 4; ++q)
                op[(size_t)q * NDIM] = acc[i][j][q] * scale + bj;
        }
    }
}

extern "C" void kernel_launch(void* const* d_in, const int* in_sizes, int n_in,
                              void* d_out, int out_size, void* d_ws, size_t ws_size,
                              hipStream_t stream) {
    const float* X     = (const float*)d_in[0];
    const int*   Wq    = (const int*)d_in[1];   // int8 widened to int32 by harness
    const float* scale = (const float*)d_in[2];
    const float* bias  = (const float*)d_in[3];
    float*       Out   = (float*)d_out;

    const size_t xBytes = (size_t)MDIM * KDIM * 2;          // 67 MB
    const size_t wBytes = (size_t)NDIM * KDIM * 2;          // 134 MB
    if (ws_size >= xBytes + wBytes) {
        ushort_t* Xbf = (ushort_t*)d_ws;
        ushort_t* Wbf = (ushort_t*)((char*)d_ws + xBytes);
        hipLaunchKernelGGL(cvt_f32_bf16, dim3(2048), dim3(256), 0, stream,
                           X, Xbf, MDIM * KDIM / 8);
        hipLaunchKernelGGL(cvt_i32_bf16, dim3(2048), dim3(256), 0, stream,
                           Wq, Wbf, NDIM * KDIM / 8);
        hipLaunchKernelGGL(sl_gemm_bf16, dim3(8192), dim3(256), 0, stream,
                           Xbf, Wbf, scale, bias, Out);
    } else {
        hipLaunchKernelGGL(sl_gemm_fb, dim3(8192), dim3(256), 0, stream,
                           X, Wq, scale, bias, Out);
    }
}

// Round 3
// 1384.943 us; speedup vs baseline: 1.9865x; 1.0390x over previous
//
#include <hip/hip_runtime.h>
#include <hip/hip_bf16.h>

typedef __attribute__((ext_vector_type(4))) float f32x4;
typedef __attribute__((ext_vector_type(4))) int   i32x4;
typedef __attribute__((ext_vector_type(8))) short s16x8;
typedef unsigned short ushort_t;

#define MDIM 8192
#define KDIM 4096
#define NDIM 16384
#define NKT  (KDIM / 32)        // 128 K-tiles of BK=32

static __device__ __forceinline__ short f2bf(float f) {
    __bf16 h = (__bf16)f;
    return __builtin_bit_cast(short, h);
}

static __device__ __forceinline__ void gload_lds16(const void* g, void* l) {
    __builtin_amdgcn_global_load_lds(
        (const __attribute__((address_space(1))) unsigned int*)g,
        (__attribute__((address_space(3))) unsigned int*)l,
        16, 0, 0);
}

// ---------------- convert kernels (memory-bound, vectorized) ----------------

__global__ __launch_bounds__(256)
void cvt_f32_bf16(const float* __restrict__ in, ushort_t* __restrict__ out, int n8) {
    for (int i = blockIdx.x * blockDim.x + threadIdx.x; i < n8;
         i += gridDim.x * blockDim.x) {
        f32x4 a = ((const f32x4*)in)[i * 2];
        f32x4 b = ((const f32x4*)in)[i * 2 + 1];
        s16x8 o;
        #pragma unroll
        for (int q = 0; q < 4; ++q) o[q] = f2bf(a[q]);
        #pragma unroll
        for (int q = 0; q < 4; ++q) o[4 + q] = f2bf(b[q]);
        ((s16x8*)out)[i] = o;
    }
}

__global__ __launch_bounds__(256)
void cvt_i32_bf16(const int* __restrict__ in, ushort_t* __restrict__ out, int n8) {
    for (int i = blockIdx.x * blockDim.x + threadIdx.x; i < n8;
         i += gridDim.x * blockDim.x) {
        i32x4 a = ((const i32x4*)in)[i * 2];
        i32x4 b = ((const i32x4*)in)[i * 2 + 1];
        s16x8 o;
        #pragma unroll
        for (int q = 0; q < 4; ++q) o[q] = f2bf((float)a[q]);   // |v|<=127: exact
        #pragma unroll
        for (int q = 0; q < 4; ++q) o[4 + q] = f2bf((float)b[q]);
        ((s16x8*)out)[i] = o;
    }
}

// ---------------- 256x256 bf16 GEMM, phase-interleaved, counted vmcnt ------
// C[m][n] = sum_k A[m][k]*B[n][k], BK=32, ring of 4 LDS K-tile buffers.
// LDS tile per buffer: A[256][32] + B[256][32] bf16 (32 KB). Rows are 64 B =
// 4 slots of 16 B; physical slot = logical ^ ((row>>1)&3)  (2-way max alias).
// Staging: global_load_lds (linear LDS dest) with inverse-swizzled global src.
// Schedule per K-tile (2 phases):
//   ph0: stage A-chunks of ktile it+2 | ds_read A-frags 0-3 + B-frags 0-3
//        | barrier | 16 MFMA | barrier
//   ph1: stage B-chunks               | ds_read A-frags 4-7
//        | barrier | 16 MFMA | vmcnt(4) | barrier
// vmcnt(4) allows only this iteration's own 4 prefetch loads to remain
// outstanding -> next K-tile's data is provably in LDS. Never drains to 0.

__global__ __launch_bounds__(512, 2)
void sl_gemm_256(const ushort_t* __restrict__ A, const ushort_t* __restrict__ Bw,
                 const float* __restrict__ scale_p, const float* __restrict__ bias,
                 float* __restrict__ Out)
{
    __shared__ char lds[131072];   // 4 bufs x (A 16 KB + B 16 KB)

    const int t    = threadIdx.x;
    const int lane = t & 63;
    const int wave = t >> 6;        // 0..7
    const int wr   = wave >> 2;     // 0..1 : 128 output rows each
    const int wc   = wave & 3;      // 0..3 : 64  output cols each

    // ---- tile mapping: XCD chunks of 256, then 16-tn panels, tm fastest
    int bid = blockIdx.x;                       // 2048 blocks (32 tm x 64 tn)
    int swz = (bid & 7) * 256 + (bid >> 3);
    int panel = swz >> 9;                       // 4 panels of 32tm x 16tn
    int inp   = swz & 511;
    int tn = (panel << 4) + (inp >> 5);
    int tm = inp & 31;
    const int m0 = tm << 8;
    const int n0 = tn << 8;

    // ---- staging geometry: thread covers row (wave*16 + lane>>2) of a
    //      128-row chunk, physical slot lane&3
    const int srow  = wave * 16 + (lane >> 2);            // 0..127
    const int sslot = lane & 3;
    const int sA    = sslot ^ ((srow >> 1) & 3);          // logical slot
    const ushort_t* pA0 = A  + (size_t)(m0 + srow) * KDIM + sA * 8;
    const ushort_t* pA1 = pA0 + (size_t)128 * KDIM;
    const ushort_t* pB0 = Bw + (size_t)(n0 + srow) * KDIM + sA * 8;
    const ushort_t* pB1 = pB0 + (size_t)128 * KDIM;
    const int ldsw = wave * 1024;                          // wave-uniform dest

    // ---- fragment read offsets (byte, buf-relative)
    const int fr = lane & 15;
    const int fs = lane >> 4;                              // 0..3
    int aoff[8], boff[4];
    #pragma unroll
    for (int i = 0; i < 8; ++i) {
        int ra = wr * 128 + i * 16 + fr;
        aoff[i] = ra * 64 + ((fs ^ ((ra >> 1) & 3)) * 16);
    }
    #pragma unroll
    for (int j = 0; j < 4; ++j) {
        int rb = wc * 64 + j * 16 + fr;
        boff[j] = 16384 + rb * 64 + ((fs ^ ((rb >> 1) & 3)) * 16);
    }

    f32x4 acc[8][4];
    #pragma unroll
    for (int i = 0; i < 8; ++i)
        #pragma unroll
        for (int j = 0; j < 4; ++j)
            acc[i][j] = (f32x4){0.f, 0.f, 0.f, 0.f};

    // ---- prologue: stage ktile0 -> buf0, ktile1 -> buf1
    #pragma unroll
    for (int kt = 0; kt < 2; ++kt) {
        const size_t ko  = (size_t)kt * 32;
        char* b = lds + kt * 32768;
        gload_lds16(pA0 + ko, b + ldsw);
        gload_lds16(pA1 + ko, b + 8192  + ldsw);
        gload_lds16(pB0 + ko, b + 16384 + ldsw);
        gload_lds16(pB1 + ko, b + 24576 + ldsw);
    }
    asm volatile("s_waitcnt vmcnt(4)" ::: "memory");   // ktile0 landed
    __builtin_amdgcn_s_barrier();
    __builtin_amdgcn_sched_barrier(0);

    for (int it = 0; it < NKT; ++it) {
        const char* rb = lds + (it & 3) * 32768;
        char*       wb = lds + ((it + 2) & 3) * 32768;
        int kq = it + 2; if (kq >= NKT) kq -= NKT;     // wraparound staging
        const size_t ko = (size_t)kq * 32;

        // ================= phase 0 =================
        gload_lds16(pA0 + ko, wb + ldsw);
        gload_lds16(pA1 + ko, wb + 8192 + ldsw);
        s16x8 af0, af1, af2, af3, bq0, bq1, bq2, bq3;
        af0 = *(const s16x8*)(rb + aoff[0]);
        af1 = *(const s16x8*)(rb + aoff[1]);
        af2 = *(const s16x8*)(rb + aoff[2]);
        af3 = *(const s16x8*)(rb + aoff[3]);
        bq0 = *(const s16x8*)(rb + boff[0]);
        bq1 = *(const s16x8*)(rb + boff[1]);
        bq2 = *(const s16x8*)(rb + boff[2]);
        bq3 = *(const s16x8*)(rb + boff[3]);
        __builtin_amdgcn_s_barrier();
        __builtin_amdgcn_sched_barrier(0);
        __builtin_amdgcn_s_setprio(1);
        acc[0][0] = __builtin_amdgcn_mfma_f32_16x16x32_bf16(af0, bq0, acc[0][0], 0, 0, 0);
        acc[0][1] = __builtin_amdgcn_mfma_f32_16x16x32_bf16(af0, bq1, acc[0][1], 0, 0, 0);
        acc[0][2] = __builtin_amdgcn_mfma_f32_16x16x32_bf16(af0, bq2, acc[0][2], 0, 0, 0);
        acc[0][3] = __builtin_amdgcn_mfma_f32_16x16x32_bf16(af0, bq3, acc[0][3], 0, 0, 0);
        acc[1][0] = __builtin_amdgcn_mfma_f32_16x16x32_bf16(af1, bq0, acc[1][0], 0, 0, 0);
        acc[1][1] = __builtin_amdgcn_mfma_f32_16x16x32_bf16(af1, bq1, acc[1][1], 0, 0, 0);
        acc[1][2] = __builtin_amdgcn_mfma_f32_16x16x32_bf16(af1, bq2, acc[1][2], 0, 0, 0);
        acc[1][3] = __builtin_amdgcn_mfma_f32_16x16x32_bf16(af1, bq3, acc[1][3], 0, 0, 0);
        acc[2][0] = __builtin_amdgcn_mfma_f32_16x16x32_bf16(af2, bq0, acc[2][0], 0, 0, 0);
        acc[2][1] = __builtin_amdgcn_mfma_f32_16x16x32_bf16(af2, bq1, acc[2][1], 0, 0, 0);
        acc[2][2] = __builtin_amdgcn_mfma_f32_16x16x32_bf16(af2, bq2, acc[2][2], 0, 0, 0);
        acc[2][3] = __builtin_amdgcn_mfma_f32_16x16x32_bf16(af2, bq3, acc[2][3], 0, 0, 0);
        acc[3][0] = __builtin_amdgcn_mfma_f32_16x16x32_bf16(af3, bq0, acc[3][0], 0, 0, 0);
        acc[3][1] = __builtin_amdgcn_mfma_f32_16x16x32_bf16(af3, bq1, acc[3][1], 0, 0, 0);
        acc[3][2] = __builtin_amdgcn_mfma_f32_16x16x32_bf16(af3, bq2, acc[3][2], 0, 0, 0);
        acc[3][3] = __builtin_amdgcn_mfma_f32_16x16x32_bf16(af3, bq3, acc[3][3], 0, 0, 0);
        __builtin_amdgcn_s_setprio(0);
        __builtin_amdgcn_s_barrier();
        __builtin_amdgcn_sched_barrier(0);

        // ================= phase 1 =================
        gload_lds16(pB0 + ko, wb + 16384 + ldsw);
        gload_lds16(pB1 + ko, wb + 24576 + ldsw);
        s16x8 ag0, ag1, ag2, ag3;
        ag0 = *(const s16x8*)(rb + aoff[4]);
        ag1 = *(const s16x8*)(rb + aoff[5]);
        ag2 = *(const s16x8*)(rb + aoff[6]);
        ag3 = *(const s16x8*)(rb + aoff[7]);
        __builtin_amdgcn_s_barrier();
        __builtin_amdgcn_sched_barrier(0);
        __builtin_amdgcn_s_setprio(1);
        acc[4][0] = __builtin_amdgcn_mfma_f32_16x16x32_bf16(ag0, bq0, acc[4][0], 0, 0, 0);
        acc[4][1] = __builtin_amdgcn_mfma_f32_16x16x32_bf16(ag0, bq1, acc[4][1], 0, 0, 0);
        acc[4][2] = __builtin_amdgcn_mfma_f32_16x16x32_bf16(ag0, bq2, acc[4][2], 0, 0, 0);
        acc[4][3] = __builtin_amdgcn_mfma_f32_16x16x32_bf16(ag0, bq3, acc[4][3], 0, 0, 0);
        acc[5][0] = __builtin_amdgcn_mfma_f32_16x16x32_bf16(ag1, bq0, acc[5][0], 0, 0, 0);
        acc[5][1] = __builtin_amdgcn_mfma_f32_16x16x32_bf16(ag1, bq1, acc[5][1], 0, 0, 0);
        acc[5][2] = __builtin_amdgcn_mfma_f32_16x16x32_bf16(ag1, bq2, acc[5][2], 0, 0, 0);
        acc[5][3] = __builtin_amdgcn_mfma_f32_16x16x32_bf16(ag1, bq3, acc[5][3], 0, 0, 0);
        acc[6][0] = __builtin_amdgcn_mfma_f32_16x16x32_bf16(ag2, bq0, acc[6][0], 0, 0, 0);
        acc[6][1] = __builtin_amdgcn_mfma_f32_16x16x32_bf16(ag2, bq1, acc[6][1], 0, 0, 0);
        acc[6][2] = __builtin_amdgcn_mfma_f32_16x16x32_bf16(ag2, bq2, acc[6][2], 0, 0, 0);
        acc[6][3] = __builtin_amdgcn_mfma_f32_16x16x32_bf16(ag2, bq3, acc[6][3], 0, 0, 0);
        acc[7][0] = __builtin_amdgcn_mfma_f32_16x16x32_bf16(ag3, bq0, acc[7][0], 0, 0, 0);
        acc[7][1] = __builtin_amdgcn_mfma_f32_16x16x32_bf16(ag3, bq1, acc[7][1], 0, 0, 0);
        acc[7][2] = __builtin_amdgcn_mfma_f32_16x16x32_bf16(ag3, bq2, acc[7][2], 0, 0, 0);
        acc[7][3] = __builtin_amdgcn_mfma_f32_16x16x32_bf16(ag3, bq3, acc[7][3], 0, 0, 0);
        __builtin_amdgcn_s_setprio(0);
        asm volatile("s_waitcnt vmcnt(4)" ::: "memory");   // counted, never 0
        __builtin_amdgcn_s_barrier();
        __builtin_amdgcn_sched_barrier(0);
    }

    // ---- epilogue: D col = lane&15, row = fs*4 + q; scale + bias
    const float scale = scale_p[0];
    #pragma unroll
    for (int j = 0; j < 4; ++j) {
        const int c   = n0 + wc * 64 + j * 16 + fr;
        const float bj = bias[c];
        #pragma unroll
        for (int i = 0; i < 8; ++i) {
            const int r0 = m0 + wr * 128 + i * 16 + fs * 4;
            float* op = Out + (size_t)r0 * NDIM + c;
            #pragma unroll
            for (int q = 0; q < 4; ++q)
                op[(size_t)q * NDIM] = acc[i][j][q] * scale + bj;
        }
    }
}

// ---------------- fallback (fp32 direct, no workspace) ----------------

__global__ __launch_bounds__(256, 2)
void sl_gemm_fb(const float* __restrict__ X, const int* __restrict__ Wq,
                const float* __restrict__ scale_p, const float* __restrict__ bias,
                float* __restrict__ Out)
{
    __shared__ s16x8 As[128 * 4];
    __shared__ s16x8 Bs[128 * 4];

    const int t    = threadIdx.x;
    const int lane = t & 63;
    const int wave = t >> 6;
    const int wr   = wave >> 1;
    const int wc   = wave & 1;

    int bid = blockIdx.x;
    int swz = (bid & 7) * 1024 + (bid >> 3);
    int panel   = swz >> 10;
    int inpanel = swz & 1023;
    int tn = (panel << 4) + (inpanel >> 6);
    int tm = inpanel & 63;
    const int m0 = tm << 7;
    const int n0 = tn << 7;

    const int srow  = t >> 1;
    const int shalf = t & 1;
    const float* Xp = X  + (size_t)(m0 + srow) * KDIM + shalf * 16;
    const int*   Wp = Wq + (size_t)(n0 + srow) * KDIM + shalf * 16;

    f32x4 acc[4][4];
    #pragma unroll
    for (int i = 0; i < 4; ++i)
        #pragma unroll
        for (int j = 0; j < 4; ++j)
            acc[i][j] = (f32x4){0.f, 0.f, 0.f, 0.f};

    const int fr = lane & 15;
    const int fs = lane >> 4;

    f32x4 ar[4];
    i32x4 br[4];
    #pragma unroll
    for (int p = 0; p < 4; ++p) {
        ar[p] = *(const f32x4*)(Xp + p * 4);
        br[p] = *(const i32x4*)(Wp + p * 4);
    }

    const int wbase = srow * 4;
    const int wswz  = (srow >> 1) & 3;
    const int ws0   = (shalf * 2)     ^ wswz;
    const int ws1   = (shalf * 2 + 1) ^ wswz;

    for (int kt = 0; kt < KDIM / 32; ++kt) {
        __syncthreads();
        {
            s16x8 v0, v1;
            #pragma unroll
            for (int q = 0; q < 8; ++q) v0[q] = f2bf(ar[q >> 2][q & 3]);
            #pragma unroll
            for (int q = 0; q < 8; ++q) v1[q] = f2bf(ar[2 + (q >> 2)][q & 3]);
            As[wbase + ws0] = v0;
            As[wbase + ws1] = v1;
            s16x8 u0, u1;
            #pragma unroll
            for (int q = 0; q < 8; ++q) u0[q] = f2bf((float)br[q >> 2][q & 3]);
            #pragma unroll
            for (int q = 0; q < 8; ++q) u1[q] = f2bf((float)br[2 + (q >> 2)][q & 3]);
            Bs[wbase + ws0] = u0;
            Bs[wbase + ws1] = u1;
        }
        __syncthreads();

        if (kt + 1 < KDIM / 32) {
            const float* Xn = Xp + (size_t)(kt + 1) * 32;
            const int*   Wn = Wp + (size_t)(kt + 1) * 32;
            #pragma unroll
            for (int p = 0; p < 4; ++p) {
                ar[p] = *(const f32x4*)(Xn + p * 4);
                br[p] = *(const i32x4*)(Wn + p * 4);
            }
        }

        s16x8 af[4], bq[4];
        #pragma unroll
        for (int i = 0; i < 4; ++i) {
            int row = wr * 64 + i * 16 + fr;
            af[i] = As[row * 4 + (fs ^ ((row >> 1) & 3))];
        }
        #pragma unroll
        for (int j = 0; j < 4; ++j) {
            int col = wc * 64 + j * 16 + fr;
            bq[j] = Bs[col * 4 + (fs ^ ((col >> 1) & 3))];
        }
        #pragma unroll
        for (int i = 0; i < 4; ++i)
            #pragma unroll
            for (int j = 0; j < 4; ++j)
                acc[i][j] = __builtin_amdgcn_mfma_f32_16x16x32_bf16(
                    af[i], bq[j], acc[i][j], 0, 0, 0);
    }

    const float scale = scale_p[0];
    #pragma unroll
    for (int j = 0; j < 4; ++j) {
        const int c  = n0 + wc * 64 + j * 16 + fr;
        const float bj = bias[c];
        #pragma unroll
        for (int i = 0; i < 4; ++i) {
            const int r0 = m0 + wr * 64 + i * 16 + fs * 4;
            float* op = Out + (size_t)r0 * NDIM + c;
            #pragma unroll
            for (int q = 0; q < 4; ++q)
                op[(size_t)q * NDIM] = acc[i][j][q] * scale + bj;
        }
    }
}

extern "C" void kernel_launch(void* const* d_in, const int* in_sizes, int n_in,
                              void* d_out, int out_size, void* d_ws, size_t ws_size,
                              hipStream_t stream) {
    const float* X     = (const float*)d_in[0];
    const int*   Wq    = (const int*)d_in[1];   // int8 widened to int32 by harness
    const float* scale = (const float*)d_in[2];
    const float* bias  = (const float*)d_in[3];
    float*       Out   = (float*)d_out;

    const size_t xBytes = (size_t)MDIM * KDIM * 2;          // 67 MB
    const size_t wBytes = (size_t)NDIM * KDIM * 2;          // 134 MB
    if (ws_size >= xBytes + wBytes) {
        ushort_t* Xbf = (ushort_t*)d_ws;
        ushort_t* Wbf = (ushort_t*)((char*)d_ws + xBytes);
        hipLaunchKernelGGL(cvt_f32_bf16, dim3(2048), dim3(256), 0, stream,
                           X, Xbf, MDIM * KDIM / 8);
        hipLaunchKernelGGL(cvt_i32_bf16, dim3(2048), dim3(256), 0, stream,
                           Wq, Wbf, NDIM * KDIM / 8);
        hipLaunchKernelGGL(sl_gemm_256, dim3(2048), dim3(512), 0, stream,
                           Xbf, Wbf, scale, bias, Out);
    } else {
        hipLaunchKernelGGL(sl_gemm_fb, dim3(8192), dim3(256), 0, stream,
                           X, Wq, scale, bias, Out);
    }
}